// Round 1
// baseline (707.473 us; speedup 1.0000x reference)
//
#include <hip/hip_runtime.h>
#include <hip/hip_bf16.h>
#include <stdint.h>

// SelfAttention: B=4, N=4096, D=1024, causal, fp32 in/out.
// Pipeline: cvt->bf16, QKV GEMM (m97-style), v-transpose, S=qk^T (lower-tri tiles),
// in-place causal softmax, O=P v^T (K-capped). All bf16 MFMA 16x16x32, fp32 accum.

typedef __attribute__((ext_vector_type(8))) short short8;
typedef __attribute__((ext_vector_type(4))) float float4v;

__device__ inline unsigned short f2b(float f) {
  union { float f; unsigned u; } v; v.f = f;
  unsigned r = (v.u + 0x7fffu + ((v.u >> 16) & 1u)) >> 16;
  return (unsigned short)r;
}
__device__ inline float b2f(unsigned short b) {
  union { unsigned u; float f; } v; v.u = ((unsigned)b) << 16;
  return v.f;
}

typedef const __attribute__((address_space(1))) unsigned int* gptr_t;
typedef __attribute__((address_space(3))) unsigned int* lptr_t;

__device__ inline void gload_lds16(const unsigned short* g, unsigned short* l) {
  __builtin_amdgcn_global_load_lds((gptr_t)(const void*)g, (lptr_t)(void*)l, 16, 0, 0);
}

// ---------------- f32 -> bf16 conversion ----------------
__global__ __launch_bounds__(256) void cvt_f32_bf16(const float* __restrict__ in,
                                                    unsigned short* __restrict__ out,
                                                    long n) {
  long i = ((long)blockIdx.x * 256 + threadIdx.x) * 4;
  long stride = (long)gridDim.x * 256 * 4;
  for (; i < n; i += stride) {
    float4 f = *(const float4*)&in[i];
    union { unsigned short u[4]; uint2 v; } o;
    o.u[0] = f2b(f.x); o.u[1] = f2b(f.y); o.u[2] = f2b(f.z); o.u[3] = f2b(f.w);
    *(uint2*)&out[i] = o.v;
  }
}

// ---------------- GEMM: C = A * B^T (+bias)*scale ----------------
// A: [M,K] bf16 row-major, B: [N,K] bf16 row-major (dot along rows of both).
// MODE 0: QKV  (bias add, scale, bf16 out)
// MODE 1: S    (skip tiles above diagonal, bf16 out)
// MODE 2: PV   (K capped at (bi+1)*128, f32 out)
template <int MODE>
__global__ __launch_bounds__(256) void gemm_bt(const unsigned short* __restrict__ Ag,
                                               const unsigned short* __restrict__ Bg,
                                               const float* __restrict__ bias,
                                               void* __restrict__ Cg,
                                               int M, int N, int K,
                                               long sA, long sB, long sC,
                                               float scale) {
  const int bi = blockIdx.x;  // M tile
  const int bj = blockIdx.y;  // N tile
  const int b = blockIdx.z;
  if (MODE == 1 && bj > bi) return;

  const unsigned short* A = Ag + (long)b * sA;
  const unsigned short* B = Bg + (long)b * sB;

  int Keff = K;
  if (MODE == 2) { int cap = (bi + 1) * 128; Keff = cap < K ? cap : K; }

  __shared__ unsigned short As[128 * 32];
  __shared__ unsigned short Bs[128 * 32];

  const int tid = threadIdx.x;
  const int w = tid >> 6, l = tid & 63;
  const int wr = w >> 1, wc = w & 1;
  const int lr = l & 15;
  const int k8 = (l >> 4) * 8;

  const int rowA0 = bi * 128;
  const int rowB0 = bj * 128;

  float4v acc[4][4];
#pragma unroll
  for (int i = 0; i < 4; i++)
#pragma unroll
    for (int j = 0; j < 4; j++) acc[i][j] = (float4v){0.f, 0.f, 0.f, 0.f};

  for (int k0 = 0; k0 < Keff; k0 += 32) {
    // stage 128x32 bf16 tiles of A and B: 512 chunks of 16B each, 2 issues/thread
#pragma unroll
    for (int i = 0; i < 2; i++) {
      int c = i * 256 + tid;
      int r = c >> 2, c8 = (c & 3) * 8;
      int ldsbase = (i * 256 + w * 64) * 8;  // wave-uniform; HW adds lane*16B
      gload_lds16(A + (long)(rowA0 + r) * K + k0 + c8, &As[ldsbase]);
      gload_lds16(B + (long)(rowB0 + r) * K + k0 + c8, &Bs[ldsbase]);
    }
    __syncthreads();

    short8 af[4], bf[4];
#pragma unroll
    for (int mi = 0; mi < 4; mi++)
      af[mi] = *(const short8*)&As[(wr * 64 + mi * 16 + lr) * 32 + k8];
#pragma unroll
    for (int ni = 0; ni < 4; ni++)
      bf[ni] = *(const short8*)&Bs[(wc * 64 + ni * 16 + lr) * 32 + k8];
#pragma unroll
    for (int mi = 0; mi < 4; mi++)
#pragma unroll
      for (int ni = 0; ni < 4; ni++)
        acc[mi][ni] = __builtin_amdgcn_mfma_f32_16x16x32_bf16(af[mi], bf[ni], acc[mi][ni], 0, 0, 0);
    __syncthreads();
  }

  // epilogue: C/D layout col=lane&15, row=(lane>>4)*4+j  [m89-verified]
  const int col0 = bj * 128 + wc * 64;
  const int row0g = bi * 128 + wr * 64;
  if (MODE == 2) {
    float* C = (float*)Cg + (long)b * sC;
#pragma unroll
    for (int mi = 0; mi < 4; mi++) {
      int rbase = row0g + mi * 16 + (l >> 4) * 4;
#pragma unroll
      for (int ni = 0; ni < 4; ni++) {
        int col = col0 + ni * 16 + lr;
#pragma unroll
        for (int j = 0; j < 4; j++)
          C[(long)(rbase + j) * N + col] = acc[mi][ni][j];
      }
    }
  } else {
    unsigned short* C = (unsigned short*)Cg + (long)b * sC;
#pragma unroll
    for (int mi = 0; mi < 4; mi++) {
      int rbase = row0g + mi * 16 + (l >> 4) * 4;
#pragma unroll
      for (int ni = 0; ni < 4; ni++) {
        int col = col0 + ni * 16 + lr;
        float bv = 0.f;
        if (MODE == 0) bv = bias[col];
#pragma unroll
        for (int j = 0; j < 4; j++)
          C[(long)(rbase + j) * N + col] = f2b((acc[mi][ni][j] + bv) * scale);
      }
    }
  }
}

// ---------------- causal softmax, in place on bf16 S ----------------
__global__ __launch_bounds__(256) void softmax_causal(unsigned short* __restrict__ S) {
  const int bid = blockIdx.x;  // 0..16383
  const int b = bid >> 12, i = bid & 4095;
  unsigned short* row = S + ((long)b * 4096 + i) * 4096;
  const int len = i + 1;
  const int padTo = ((i >> 7) + 1) << 7;  // zero-fill to 128-block boundary for PV
  const int nch = padTo >> 3;             // 16B chunks (<=512)
  const int tid = threadIdx.x;
  const int w = tid >> 6;

  float v[2][8];
  int nc[2];
  float m = -3e38f;
#pragma unroll
  for (int s = 0; s < 2; s++) {
    int c = tid + s * 256;
    nc[s] = -1;
    if (c < nch) {
      nc[s] = c;
      short8 x = *(const short8*)&row[c * 8];
#pragma unroll
      for (int j = 0; j < 8; j++) {
        int idx = c * 8 + j;
        float f = (idx < len) ? b2f((unsigned short)x[j]) : -3e38f;
        v[s][j] = f;
        m = fmaxf(m, f);
      }
    }
  }

  __shared__ float red[4];
#pragma unroll
  for (int off = 32; off; off >>= 1) m = fmaxf(m, __shfl_xor(m, off));
  if ((tid & 63) == 0) red[w] = m;
  __syncthreads();
  m = fmaxf(fmaxf(red[0], red[1]), fmaxf(red[2], red[3]));

  float sum = 0.f;
#pragma unroll
  for (int s = 0; s < 2; s++) {
    if (nc[s] >= 0) {
#pragma unroll
      for (int j = 0; j < 8; j++) {
        float e = __expf(v[s][j] - m);
        v[s][j] = e;
        sum += e;
      }
    }
  }
  __syncthreads();  // protect red before reuse
#pragma unroll
  for (int off = 32; off; off >>= 1) sum += __shfl_xor(sum, off);
  if ((tid & 63) == 0) red[w] = sum;
  __syncthreads();
  sum = red[0] + red[1] + red[2] + red[3];
  const float inv = 1.0f / sum;

#pragma unroll
  for (int s = 0; s < 2; s++) {
    if (nc[s] >= 0) {
      int c = nc[s];
      short8 o;
#pragma unroll
      for (int j = 0; j < 8; j++) o[j] = (short)f2b(v[s][j] * inv);
      *(short8*)&row[c * 8] = o;
    }
  }
}

// ---------------- v transpose: [4][4096][1024] -> [4][1024][4096] ----------------
__global__ __launch_bounds__(256) void transpose_v(const unsigned short* __restrict__ V,
                                                   unsigned short* __restrict__ VT) {
  __shared__ unsigned short t[64][65];  // 65: conflict-free column gather
  const int b = blockIdx.z;
  const int n0 = blockIdx.x * 64;
  const int d0 = blockIdx.y * 64;
  const unsigned short* Vb = V + (long)b * 4096 * 1024;
  unsigned short* VTb = VT + (long)b * 1024 * 4096;
  const int tid = threadIdx.x;
#pragma unroll
  for (int s = 0; s < 2; s++) {
    int c = s * 256 + tid;
    int r = c >> 3, c8 = (c & 7) * 8;
    short8 x = *(const short8*)&Vb[(long)(n0 + r) * 1024 + d0 + c8];
#pragma unroll
    for (int j = 0; j < 8; j++) t[r][c8 + j] = (unsigned short)x[j];
  }
  __syncthreads();
#pragma unroll
  for (int s = 0; s < 2; s++) {
    int c = s * 256 + tid;
    int dr = c >> 3, n8 = (c & 7) * 8;
    short8 o;
#pragma unroll
    for (int j = 0; j < 8; j++) o[j] = (short)t[n8 + j][dr];
    *(short8*)&VTb[(long)(d0 + dr) * 4096 + n0 + n8] = o;
  }
}

extern "C" void kernel_launch(void* const* d_in, const int* in_sizes, int n_in,
                              void* d_out, int out_size, void* d_ws, size_t ws_size,
                              hipStream_t stream) {
  const float* x  = (const float*)d_in[0];
  const float* Wq = (const float*)d_in[1];
  const float* bq = (const float*)d_in[2];
  const float* Wk = (const float*)d_in[3];
  const float* bk = (const float*)d_in[4];
  const float* Wv = (const float*)d_in[5];
  const float* bv = (const float*)d_in[6];
  float* out = (float*)d_out;

  const long NTOK = 16384L;        // 4*4096
  const long D = 1024L;
  const long NB = 4096L;           // seq len per batch

  unsigned short* ws = (unsigned short*)d_ws;
  unsigned short* qb = ws;                    // 16384x1024
  unsigned short* kb = qb + NTOK * D;
  unsigned short* vb = kb + NTOK * D;
  unsigned short* vT = vb + NTOK * D;         // [4][1024][4096]
  unsigned short* S  = vT + NTOK * D;         // [4][4096][4096] bf16 (128MB)
  // xb/Wb overlap the S region (consumed before S is written)
  unsigned short* xb  = S;
  unsigned short* Wqb = S + NTOK * D;
  unsigned short* Wkb = Wqb + D * D;
  unsigned short* Wvb = Wkb + D * D;

  // 1) conversions
  cvt_f32_bf16<<<2048, 256, 0, stream>>>(x, xb, NTOK * D);
  cvt_f32_bf16<<<512, 256, 0, stream>>>(Wq, Wqb, D * D);
  cvt_f32_bf16<<<512, 256, 0, stream>>>(Wk, Wkb, D * D);
  cvt_f32_bf16<<<512, 256, 0, stream>>>(Wv, Wvb, D * D);

  // 2) QKV projections: [16384,1024] x [1024,1024]^T
  dim3 gqkv(128, 8, 1);
  gemm_bt<0><<<gqkv, 256, 0, stream>>>(xb, Wqb, bq, qb, 16384, 1024, 1024, 0, 0, 0, 0.03125f);
  gemm_bt<0><<<gqkv, 256, 0, stream>>>(xb, Wkb, bk, kb, 16384, 1024, 1024, 0, 0, 0, 1.0f);
  gemm_bt<0><<<gqkv, 256, 0, stream>>>(xb, Wvb, bv, vb, 16384, 1024, 1024, 0, 0, 0, 1.0f);

  // 3) v transpose
  transpose_v<<<dim3(64, 16, 4), 256, 0, stream>>>(vb, vT);

  // 4) S = q k^T per batch (lower-triangular tiles only)
  gemm_bt<1><<<dim3(32, 32, 4), 256, 0, stream>>>(qb, kb, nullptr, S,
      4096, 4096, 1024, NB * D, NB * D, NB * NB, 1.0f);

  // 5) causal softmax in place
  softmax_causal<<<16384, 256, 0, stream>>>(S);

  // 6) O = P vT per batch, K capped per row-block
  gemm_bt<2><<<dim3(32, 8, 4), 256, 0, stream>>>(S, vT, nullptr, out,
      4096, 1024, 4096, NB * NB, D * NB, NB * D, 1.0f);
}

// Round 2
// 539.631 us; speedup vs baseline: 1.3110x; 1.3110x over previous
//
#include <hip/hip_runtime.h>
#include <hip/hip_bf16.h>
#include <stdint.h>

// SelfAttention: B=4, N=4096, D=1024, causal, fp32 in/out.
// R2: PV bi-pairing (load balance), fused QKV GEMM (one dispatch over [3072,1024]
// concat weights), tri-packed S grid, single cvt kernel. GEMM core unchanged (m97-style).

typedef __attribute__((ext_vector_type(8))) short short8;
typedef __attribute__((ext_vector_type(4))) float float4v;

__device__ inline unsigned short f2b(float f) {
  union { float f; unsigned u; } v; v.f = f;
  unsigned r = (v.u + 0x7fffu + ((v.u >> 16) & 1u)) >> 16;
  return (unsigned short)r;
}
__device__ inline float b2f(unsigned short b) {
  union { unsigned u; float f; } v; v.u = ((unsigned)b) << 16;
  return v.f;
}

typedef const __attribute__((address_space(1))) unsigned int* gptr_t;
typedef __attribute__((address_space(3))) unsigned int* lptr_t;

__device__ inline void gload_lds16(const unsigned short* g, unsigned short* l) {
  __builtin_amdgcn_global_load_lds((gptr_t)(const void*)g, (lptr_t)(void*)l, 16, 0, 0);
}

// ---------------- f32 -> bf16 conversion, all 4 tensors in one launch --------
// blocks [0,2048): x (16.7M elems, grid-stride); [2048, 2048+3*256): Wq/Wk/Wv.
__global__ __launch_bounds__(256) void cvt_all(const float* __restrict__ x,
                                               const float* __restrict__ wq,
                                               const float* __restrict__ wk,
                                               const float* __restrict__ wv,
                                               unsigned short* __restrict__ xb,
                                               unsigned short* __restrict__ wb) {
  const float* src;
  unsigned short* dst;
  long n;
  long i0;
  long stride;
  if (blockIdx.x < 2048) {
    src = x; dst = xb; n = 16384L * 1024;
    i0 = ((long)blockIdx.x * 256 + threadIdx.x) * 4;
    stride = 2048L * 256 * 4;
  } else {
    int wsec = (blockIdx.x - 2048) >> 8;       // 0,1,2
    int blk = (blockIdx.x - 2048) & 255;
    src = wsec == 0 ? wq : (wsec == 1 ? wk : wv);
    dst = wb + (long)wsec * 1024 * 1024;
    n = 1024L * 1024;
    i0 = ((long)blk * 256 + threadIdx.x) * 4;
    stride = 256L * 256 * 4;
  }
  for (long i = i0; i < n; i += stride) {
    float4 f = *(const float4*)&src[i];
    union { unsigned short u[4]; uint2 v; } o;
    o.u[0] = f2b(f.x); o.u[1] = f2b(f.y); o.u[2] = f2b(f.z); o.u[3] = f2b(f.w);
    *(uint2*)&dst[i] = o.v;
  }
}

// ---------------- GEMM: C = A * B^T ----------------
// A: [M,K] bf16 row-major, B: [N,K] bf16 row-major (dot along rows of both).
// MODE 0: fused QKV (B = concat Wq|Wk|Wv [3072,1024]; bias+scale per 1024-col
//         section; bf16 out into contiguous q|k|v [3*16384,1024])
// MODE 1: S    (tri-packed 1D grid over lower-tri tiles, bf16 out stride N)
// MODE 2: PV   (paired row-blocks bi and 31-bi for uniform work; K capped at
//         (bi+1)*128; f32 out stride N)
template <int MODE>
__global__ __launch_bounds__(256) void gemm_bt(const unsigned short* __restrict__ Ag,
                                               const unsigned short* __restrict__ Bg,
                                               const float* __restrict__ b0,
                                               const float* __restrict__ b1,
                                               const float* __restrict__ b2,
                                               void* __restrict__ Cg,
                                               int N, int K,
                                               long sA, long sB, long sC) {
  const int b = blockIdx.z;
  const unsigned short* A = Ag + (long)b * sA;
  const unsigned short* B = Bg + (long)b * sB;

  int biArr[2];
  int bj;
  if (MODE == 0) {
    biArr[0] = blockIdx.x; bj = blockIdx.y;
  } else if (MODE == 1) {
    int t = blockIdx.x;
    int bi = (int)((sqrtf(8.0f * t + 1.0f) - 1.0f) * 0.5f);
    while ((bi + 1) * (bi + 2) / 2 <= t) bi++;
    while (bi * (bi + 1) / 2 > t) bi--;
    biArr[0] = bi; bj = t - bi * (bi + 1) / 2;
  } else {
    biArr[0] = blockIdx.x; biArr[1] = 31 - (int)blockIdx.x; bj = blockIdx.y;
  }

  __shared__ unsigned short As[128 * 32];
  __shared__ unsigned short Bs[128 * 32];

  const int tid = threadIdx.x;
  const int w = tid >> 6, l = tid & 63;
  const int wr = w >> 1, wc = w & 1;
  const int lr = l & 15;
  const int k8 = (l >> 4) * 8;
  const int rowB0 = bj * 128;

  const int NT = (MODE == 2) ? 2 : 1;
#pragma unroll
  for (int tt = 0; tt < NT; tt++) {
    const int bi = biArr[tt];
    const int rowA0 = bi * 128;
    int Keff = K;
    if (MODE == 2) { int cap = (bi + 1) * 128; Keff = cap < K ? cap : K; }

    float4v acc[4][4];
#pragma unroll
    for (int i = 0; i < 4; i++)
#pragma unroll
      for (int j = 0; j < 4; j++) acc[i][j] = (float4v){0.f, 0.f, 0.f, 0.f};

    for (int k0 = 0; k0 < Keff; k0 += 32) {
#pragma unroll
      for (int i = 0; i < 2; i++) {
        int c = i * 256 + tid;
        int r = c >> 2, c8 = (c & 3) * 8;
        int ldsbase = (i * 256 + w * 64) * 8;  // wave-uniform; HW adds lane*16B
        gload_lds16(A + (long)(rowA0 + r) * K + k0 + c8, &As[ldsbase]);
        gload_lds16(B + (long)(rowB0 + r) * K + k0 + c8, &Bs[ldsbase]);
      }
      __syncthreads();

      short8 af[4], bf[4];
#pragma unroll
      for (int mi = 0; mi < 4; mi++)
        af[mi] = *(const short8*)&As[(wr * 64 + mi * 16 + lr) * 32 + k8];
#pragma unroll
      for (int ni = 0; ni < 4; ni++)
        bf[ni] = *(const short8*)&Bs[(wc * 64 + ni * 16 + lr) * 32 + k8];
#pragma unroll
      for (int mi = 0; mi < 4; mi++)
#pragma unroll
        for (int ni = 0; ni < 4; ni++)
          acc[mi][ni] = __builtin_amdgcn_mfma_f32_16x16x32_bf16(af[mi], bf[ni], acc[mi][ni], 0, 0, 0);
      __syncthreads();
    }

    // epilogue: C/D layout col=lane&15, row=(lane>>4)*4+j  [m89-verified]
    const int col0 = bj * 128 + wc * 64;
    const int row0g = bi * 128 + wr * 64;
    if (MODE == 0) {
      const int sec = bj >> 3;  // 0=q, 1=k, 2=v
      const float* bias = sec == 0 ? b0 : (sec == 1 ? b1 : b2);
      const float scale = sec == 0 ? 0.03125f : 1.0f;
      unsigned short* C = (unsigned short*)Cg + (long)sec * 16777216L;
      const int colBase = col0 - (sec << 10);
#pragma unroll
      for (int mi = 0; mi < 4; mi++) {
        int rbase = row0g + mi * 16 + (l >> 4) * 4;
#pragma unroll
        for (int ni = 0; ni < 4; ni++) {
          int col = colBase + ni * 16 + lr;
          float bvv = bias[col];
#pragma unroll
          for (int j = 0; j < 4; j++)
            C[(long)(rbase + j) * 1024 + col] = f2b((acc[mi][ni][j] + bvv) * scale);
        }
      }
    } else if (MODE == 1) {
      unsigned short* C = (unsigned short*)Cg + (long)b * sC;
#pragma unroll
      for (int mi = 0; mi < 4; mi++) {
        int rbase = row0g + mi * 16 + (l >> 4) * 4;
#pragma unroll
        for (int ni = 0; ni < 4; ni++) {
          int col = col0 + ni * 16 + lr;
#pragma unroll
          for (int j = 0; j < 4; j++)
            C[(long)(rbase + j) * N + col] = f2b(acc[mi][ni][j]);
        }
      }
    } else {
      float* C = (float*)Cg + (long)b * sC;
#pragma unroll
      for (int mi = 0; mi < 4; mi++) {
        int rbase = row0g + mi * 16 + (l >> 4) * 4;
#pragma unroll
        for (int ni = 0; ni < 4; ni++) {
          int col = col0 + ni * 16 + lr;
#pragma unroll
          for (int j = 0; j < 4; j++)
            C[(long)(rbase + j) * N + col] = acc[mi][ni][j];
        }
      }
    }
  }
}

// ---------------- causal softmax, in place on bf16 S ----------------
__global__ __launch_bounds__(256) void softmax_causal(unsigned short* __restrict__ S) {
  const int bid = blockIdx.x;  // 0..16383
  const int b = bid >> 12, i = bid & 4095;
  unsigned short* row = S + ((long)b * 4096 + i) * 4096;
  const int len = i + 1;
  const int padTo = ((i >> 7) + 1) << 7;  // zero-fill to 128-block boundary for PV
  const int nch = padTo >> 3;             // 16B chunks (<=512)
  const int tid = threadIdx.x;
  const int w = tid >> 6;

  float v[2][8];
  int nc[2];
  float m = -3e38f;
#pragma unroll
  for (int s = 0; s < 2; s++) {
    int c = tid + s * 256;
    nc[s] = -1;
    if (c < nch) {
      nc[s] = c;
      short8 x = *(const short8*)&row[c * 8];
#pragma unroll
      for (int j = 0; j < 8; j++) {
        int idx = c * 8 + j;
        float f = (idx < len) ? b2f((unsigned short)x[j]) : -3e38f;
        v[s][j] = f;
        m = fmaxf(m, f);
      }
    }
  }

  __shared__ float red[4];
#pragma unroll
  for (int off = 32; off; off >>= 1) m = fmaxf(m, __shfl_xor(m, off));
  if ((tid & 63) == 0) red[w] = m;
  __syncthreads();
  m = fmaxf(fmaxf(red[0], red[1]), fmaxf(red[2], red[3]));

  float sum = 0.f;
#pragma unroll
  for (int s = 0; s < 2; s++) {
    if (nc[s] >= 0) {
#pragma unroll
      for (int j = 0; j < 8; j++) {
        float e = __expf(v[s][j] - m);
        v[s][j] = e;
        sum += e;
      }
    }
  }
  __syncthreads();  // protect red before reuse
#pragma unroll
  for (int off = 32; off; off >>= 1) sum += __shfl_xor(sum, off);
  if ((tid & 63) == 0) red[w] = sum;
  __syncthreads();
  sum = red[0] + red[1] + red[2] + red[3];
  const float inv = 1.0f / sum;

#pragma unroll
  for (int s = 0; s < 2; s++) {
    if (nc[s] >= 0) {
      int c = nc[s];
      short8 o;
#pragma unroll
      for (int j = 0; j < 8; j++) o[j] = (short)f2b(v[s][j] * inv);
      *(short8*)&row[c * 8] = o;
    }
  }
}

// ---------------- v transpose: [4][4096][1024] -> [4][1024][4096] ----------------
__global__ __launch_bounds__(256) void transpose_v(const unsigned short* __restrict__ V,
                                                   unsigned short* __restrict__ VT) {
  __shared__ unsigned short t[64][65];  // 65: conflict-free column gather
  const int b = blockIdx.z;
  const int n0 = blockIdx.x * 64;
  const int d0 = blockIdx.y * 64;
  const unsigned short* Vb = V + (long)b * 4096 * 1024;
  unsigned short* VTb = VT + (long)b * 1024 * 4096;
  const int tid = threadIdx.x;
#pragma unroll
  for (int s = 0; s < 2; s++) {
    int c = s * 256 + tid;
    int r = c >> 3, c8 = (c & 7) * 8;
    short8 x = *(const short8*)&Vb[(long)(n0 + r) * 1024 + d0 + c8];
#pragma unroll
    for (int j = 0; j < 8; j++) t[r][c8 + j] = (unsigned short)x[j];
  }
  __syncthreads();
#pragma unroll
  for (int s = 0; s < 2; s++) {
    int c = s * 256 + tid;
    int dr = c >> 3, n8 = (c & 7) * 8;
    short8 o;
#pragma unroll
    for (int j = 0; j < 8; j++) o[j] = (short)t[n8 + j][dr];
    *(short8*)&VTb[(long)(d0 + dr) * 4096 + n0 + n8] = o;
  }
}

extern "C" void kernel_launch(void* const* d_in, const int* in_sizes, int n_in,
                              void* d_out, int out_size, void* d_ws, size_t ws_size,
                              hipStream_t stream) {
  const float* x  = (const float*)d_in[0];
  const float* Wq = (const float*)d_in[1];
  const float* bq = (const float*)d_in[2];
  const float* Wk = (const float*)d_in[3];
  const float* bk = (const float*)d_in[4];
  const float* Wv = (const float*)d_in[5];
  const float* bv = (const float*)d_in[6];
  float* out = (float*)d_out;

  const long NTOK = 16384L;        // 4*4096
  const long D = 1024L;
  const long NB = 4096L;           // seq len per batch

  unsigned short* ws = (unsigned short*)d_ws;
  unsigned short* qb = ws;                    // q|k|v contiguous: 3 x [16384,1024]
  unsigned short* kb = qb + NTOK * D;
  unsigned short* vb = kb + NTOK * D;
  unsigned short* vT = vb + NTOK * D;         // [4][1024][4096]
  unsigned short* S  = vT + NTOK * D;         // [4][4096][4096] bf16 (128MB)
  // xb/Wb overlap the S region (consumed before S is written)
  unsigned short* xb  = S;
  unsigned short* Wb  = S + NTOK * D;         // concat Wq|Wk|Wv [3072,1024]

  // 1) conversions (one launch)
  cvt_all<<<2048 + 3 * 256, 256, 0, stream>>>(x, Wq, Wk, Wv, xb, Wb);

  // 2) fused QKV projection: [16384,1024] x [3072,1024]^T
  gemm_bt<0><<<dim3(128, 24, 1), 256, 0, stream>>>(xb, Wb, bq, bk, bv, qb,
      1024, 1024, 0, 0, 0);

  // 3) v transpose
  transpose_v<<<dim3(64, 16, 4), 256, 0, stream>>>(vb, vT);

  // 4) S = q k^T per batch, tri-packed lower-triangular tiles
  gemm_bt<1><<<dim3(528, 1, 4), 256, 0, stream>>>(qb, kb, nullptr, nullptr, nullptr, S,
      4096, 1024, NB * D, NB * D, NB * NB);

  // 5) causal softmax in place
  softmax_causal<<<16384, 256, 0, stream>>>(S);

  // 6) O = P vT per batch, paired row-blocks for uniform work
  gemm_bt<2><<<dim3(16, 8, 4), 256, 0, stream>>>(S, vT, nullptr, nullptr, nullptr, out,
      1024, 4096, NB * NB, D * NB, NB * D);
}

// Round 3
// 493.879 us; speedup vs baseline: 1.4325x; 1.0926x over previous
//
#include <hip/hip_runtime.h>
#include <hip/hip_bf16.h>
#include <stdint.h>

// SelfAttention: B=4, N=4096, D=1024, causal, fp32 in/out.
// R3: QKV and S GEMMs ported to 256x256/BK=64 8-phase schedule (T2 swizzle +
// T3/T4 counted-vmcnt + T5 setprio). PV stays on the 128^2 paired kernel.

typedef __attribute__((ext_vector_type(8))) short short8;
typedef __attribute__((ext_vector_type(4))) float float4v;

__device__ inline unsigned short f2b(float f) {
  union { float f; unsigned u; } v; v.f = f;
  unsigned r = (v.u + 0x7fffu + ((v.u >> 16) & 1u)) >> 16;
  return (unsigned short)r;
}
__device__ inline float b2f(unsigned short b) {
  union { unsigned u; float f; } v; v.u = ((unsigned)b) << 16;
  return v.f;
}

typedef const __attribute__((address_space(1))) unsigned int* gptr_t;
typedef __attribute__((address_space(3))) unsigned int* lptr_t;

__device__ inline void gload_lds16(const unsigned short* g, unsigned short* l) {
  __builtin_amdgcn_global_load_lds((gptr_t)(const void*)g, (lptr_t)(void*)l, 16, 0, 0);
}

// ---------------- f32 -> bf16 conversion, all 4 tensors in one launch --------
__global__ __launch_bounds__(256) void cvt_all(const float* __restrict__ x,
                                               const float* __restrict__ wq,
                                               const float* __restrict__ wk,
                                               const float* __restrict__ wv,
                                               unsigned short* __restrict__ xb,
                                               unsigned short* __restrict__ wb) {
  const float* src;
  unsigned short* dst;
  long n, i0, stride;
  if (blockIdx.x < 2048) {
    src = x; dst = xb; n = 16384L * 1024;
    i0 = ((long)blockIdx.x * 256 + threadIdx.x) * 4;
    stride = 2048L * 256 * 4;
  } else {
    int wsec = (blockIdx.x - 2048) >> 8;
    int blk = (blockIdx.x - 2048) & 255;
    src = wsec == 0 ? wq : (wsec == 1 ? wk : wv);
    dst = wb + (long)wsec * 1024 * 1024;
    n = 1024L * 1024;
    i0 = ((long)blk * 256 + threadIdx.x) * 4;
    stride = 256L * 256 * 4;
  }
  for (long i = i0; i < n; i += stride) {
    float4 f = *(const float4*)&src[i];
    union { unsigned short u[4]; uint2 v; } o;
    o.u[0] = f2b(f.x); o.u[1] = f2b(f.y); o.u[2] = f2b(f.z); o.u[3] = f2b(f.w);
    *(uint2*)&dst[i] = o.v;
  }
}

// ================= 256x256 / BK=64 / 8-wave 8-phase GEMM =================
// C = A * B^T, A:[M,1024] bf16, B:[N,1024] bf16, both row-major, K=1024.
// LDS per buffer: A-tile 32KB as [kk][256 rows][32 cols], B-tile same. 2 buffers.
// Stage regions = K-halves (16KB, 2 global_load_lds/thread). Read swizzle:
// byte bits 4-5 ^= bits 7-8 (2-way conflict, free); source chunks pre-swizzled.
// MODE 0: fused QKV (sections q|k|v with bias+scale). MODE 1: S lower-tri tiles.

__device__ __forceinline__ void stage_half(const unsigned short* __restrict__ g,
                                           int grow0, int tile, int kk,
                                           char* tb, int tid) {
  const int kc = tile * 64 + kk * 32;
#pragma unroll
  for (int j = 0; j < 2; j++) {
    int c = j * 512 + tid;
    int lc = c ^ ((c >> 3) & 3);  // inverse of read-side swizzle, chunk-granular
    gload_lds16(g + (long)(grow0 + (lc >> 2)) * 1024 + kc + (lc & 3) * 8,
                (unsigned short*)(tb + kk * 16384 + (j * 512 + (tid & 448)) * 16));
  }
}

#define DSA(dst, TB, kk, mi) do { \
  int o = (kk) * 16384 + (wr * 128 + (mi) * 16 + lr) * 64 + g16; \
  o ^= ((o >> 3) & 0x30); dst = *(const short8*)((TB) + o); } while (0)
#define DSB(dst, TB, kk, ni) do { \
  int o = (kk) * 16384 + (wc * 64 + (ni) * 16 + lr) * 64 + g16; \
  o ^= ((o >> 3) & 0x30); dst = *(const short8*)((TB) + o); } while (0)

#define MF(x, y, z) __builtin_amdgcn_mfma_f32_16x16x32_bf16(x, y, z, 0, 0, 0)
#define MMQ(M0) \
  acc[M0 + 0][0] = MF(a0, b0, acc[M0 + 0][0]); \
  acc[M0 + 0][1] = MF(a0, b1, acc[M0 + 0][1]); \
  acc[M0 + 0][2] = MF(a0, b2, acc[M0 + 0][2]); \
  acc[M0 + 0][3] = MF(a0, b3, acc[M0 + 0][3]); \
  acc[M0 + 1][0] = MF(a1, b0, acc[M0 + 1][0]); \
  acc[M0 + 1][1] = MF(a1, b1, acc[M0 + 1][1]); \
  acc[M0 + 1][2] = MF(a1, b2, acc[M0 + 1][2]); \
  acc[M0 + 1][3] = MF(a1, b3, acc[M0 + 1][3]); \
  acc[M0 + 2][0] = MF(a2, b0, acc[M0 + 2][0]); \
  acc[M0 + 2][1] = MF(a2, b1, acc[M0 + 2][1]); \
  acc[M0 + 2][2] = MF(a2, b2, acc[M0 + 2][2]); \
  acc[M0 + 2][3] = MF(a2, b3, acc[M0 + 2][3]); \
  acc[M0 + 3][0] = MF(a3, b0, acc[M0 + 3][0]); \
  acc[M0 + 3][1] = MF(a3, b1, acc[M0 + 3][1]); \
  acc[M0 + 3][2] = MF(a3, b2, acc[M0 + 3][2]); \
  acc[M0 + 3][3] = MF(a3, b3, acc[M0 + 3][3]);

// Region read-liveness per tile: A-K0 ph1-2, A-K1 ph3-4, B-K0 ph1, B-K1 ph3.
// Stage schedule (into region last read >=1 barrier earlier):
//   ph1: A-K1(t+1)->other buf; ph2: B-K0(t+2)->this; ph3: A-K0(t+2)->this;
//   ph4: B-K1(t+2)->this; vmcnt(6) at tile end => tile t+1 fully landed.
#define KTILE(AT, BT, OA, t) do { \
  short8 a0, a1, a2, a3, b0, b1, b2, b3; \
  /* phase 1: kk0, mi 0-3 */ \
  DSB(b0, BT, 0, 0); DSB(b1, BT, 0, 1); DSB(b2, BT, 0, 2); DSB(b3, BT, 0, 3); \
  DSA(a0, AT, 0, 0); DSA(a1, AT, 0, 1); DSA(a2, AT, 0, 2); DSA(a3, AT, 0, 3); \
  if ((t) + 1 < NT) stage_half(A, rowA0, (t) + 1, 1, OA, tid); \
  __builtin_amdgcn_s_barrier(); \
  __builtin_amdgcn_s_setprio(1); MMQ(0); __builtin_amdgcn_s_setprio(0); \
  __builtin_amdgcn_s_barrier(); \
  /* phase 2: kk0, mi 4-7 (B reused from regs) */ \
  DSA(a0, AT, 0, 4); DSA(a1, AT, 0, 5); DSA(a2, AT, 0, 6); DSA(a3, AT, 0, 7); \
  if ((t) + 2 < NT) stage_half(Bm, rowB0, (t) + 2, 0, BT, tid); \
  __builtin_amdgcn_s_barrier(); \
  __builtin_amdgcn_s_setprio(1); MMQ(4); __builtin_amdgcn_s_setprio(0); \
  __builtin_amdgcn_s_barrier(); \
  /* phase 3: kk1, mi 0-3 */ \
  DSB(b0, BT, 1, 0); DSB(b1, BT, 1, 1); DSB(b2, BT, 1, 2); DSB(b3, BT, 1, 3); \
  DSA(a0, AT, 1, 0); DSA(a1, AT, 1, 1); DSA(a2, AT, 1, 2); DSA(a3, AT, 1, 3); \
  if ((t) + 2 < NT) stage_half(A, rowA0, (t) + 2, 0, AT, tid); \
  __builtin_amdgcn_s_barrier(); \
  __builtin_amdgcn_s_setprio(1); MMQ(0); __builtin_amdgcn_s_setprio(0); \
  __builtin_amdgcn_s_barrier(); \
  /* phase 4: kk1, mi 4-7 */ \
  DSA(a0, AT, 1, 4); DSA(a1, AT, 1, 5); DSA(a2, AT, 1, 6); DSA(a3, AT, 1, 7); \
  if ((t) + 2 < NT) stage_half(Bm, rowB0, (t) + 2, 1, BT, tid); \
  __builtin_amdgcn_s_barrier(); \
  __builtin_amdgcn_s_setprio(1); MMQ(4); __builtin_amdgcn_s_setprio(0); \
  if ((t) + 2 < NT) { asm volatile("s_waitcnt vmcnt(6)" ::: "memory"); } \
  else               { asm volatile("s_waitcnt vmcnt(0)" ::: "memory"); } \
  __builtin_amdgcn_s_barrier(); \
} while (0)

template <int MODE>
__global__ __launch_bounds__(512, 2) void gemm8p(
    const unsigned short* __restrict__ Ag, const unsigned short* __restrict__ Bg,
    const float* __restrict__ b0v, const float* __restrict__ b1v,
    const float* __restrict__ b2v, void* __restrict__ Cg,
    long sA, long sB, long sC) {
  __shared__ __align__(16) char smem[131072];
  const int NT = 16;  // K=1024 / 64

  int bi, bj, b;
  if (MODE == 0) {
    bi = blockIdx.x; bj = blockIdx.y; b = 0;
  } else {
    int t = blockIdx.x % 136;
    b = blockIdx.x / 136;
    int r = (int)((sqrtf(8.0f * t + 1.0f) - 1.0f) * 0.5f);
    while ((r + 1) * (r + 2) / 2 <= t) r++;
    while (r * (r + 1) / 2 > t) r--;
    bi = r; bj = t - r * (r + 1) / 2;
  }

  const unsigned short* A = Ag + (long)b * sA;
  const unsigned short* Bm = Bg + (long)b * sB;

  const int tid = threadIdx.x;
  const int l = tid & 63, w = tid >> 6;
  const int wr = w >> 2, wc = w & 3;
  const int lr = l & 15, g16 = (l >> 4) * 16;
  const int rowA0 = bi * 256, rowB0 = bj * 256;

  char* A0 = smem;
  char* B0 = smem + 32768;
  char* A1 = smem + 65536;
  char* B1 = smem + 98304;

  float4v acc[8][4];
#pragma unroll
  for (int i = 0; i < 8; i++)
#pragma unroll
    for (int j = 0; j < 4; j++) acc[i][j] = (float4v){0.f, 0.f, 0.f, 0.f};

  // prologue: tile0 (4 halves) + tile1's first 3 halves; leave 3 in flight
  stage_half(A, rowA0, 0, 0, A0, tid);
  stage_half(Bm, rowB0, 0, 0, B0, tid);
  stage_half(A, rowA0, 0, 1, A0, tid);
  stage_half(Bm, rowB0, 0, 1, B0, tid);
  stage_half(Bm, rowB0, 1, 0, B1, tid);
  stage_half(A, rowA0, 1, 0, A1, tid);
  stage_half(Bm, rowB0, 1, 1, B1, tid);
  asm volatile("s_waitcnt vmcnt(6)" ::: "memory");
  __builtin_amdgcn_s_barrier();

#pragma unroll 1
  for (int t = 0; t < NT; t += 2) {
    KTILE(A0, B0, A1, t);
    KTILE(A1, B1, A0, t + 1);
  }

  // epilogue: C/D frag layout col=lane&15, row=(lane>>4)*4+j  [m89]
  if (MODE == 0) {
    const int sec = bj >> 2;  // 0=q,1=k,2=v (4 bj-tiles per 1024-col section)
    const float* bias = sec == 0 ? b0v : (sec == 1 ? b1v : b2v);
    const float scale = sec == 0 ? 0.03125f : 1.0f;
    unsigned short* C = (unsigned short*)Cg + (long)sec * 16777216L;
    const int colbase = (bj & 3) * 256 + wc * 64;
#pragma unroll
    for (int mi = 0; mi < 8; mi++) {
      int rbase = bi * 256 + wr * 128 + mi * 16 + (l >> 4) * 4;
#pragma unroll
      for (int ni = 0; ni < 4; ni++) {
        int col = colbase + ni * 16 + lr;
        float bb = bias[col];
#pragma unroll
        for (int j = 0; j < 4; j++)
          C[(long)(rbase + j) * 1024 + col] = f2b((acc[mi][ni][j] + bb) * scale);
      }
    }
  } else {
    unsigned short* C = (unsigned short*)Cg + (long)b * sC;
#pragma unroll
    for (int mi = 0; mi < 8; mi++) {
      int rbase = bi * 256 + wr * 128 + mi * 16 + (l >> 4) * 4;
#pragma unroll
      for (int ni = 0; ni < 4; ni++) {
        int col = bj * 256 + wc * 64 + ni * 16 + lr;
#pragma unroll
        for (int j = 0; j < 4; j++)
          C[(long)(rbase + j) * 4096 + col] = f2b(acc[mi][ni][j]);
      }
    }
  }
}

// ================= PV: 128^2 m97-structure, paired row-blocks =================
__global__ __launch_bounds__(256) void gemm_pv(const unsigned short* __restrict__ Ag,
                                               const unsigned short* __restrict__ Bg,
                                               float* __restrict__ Cg,
                                               int N, int K,
                                               long sA, long sB, long sC) {
  const int b = blockIdx.z;
  const unsigned short* A = Ag + (long)b * sA;
  const unsigned short* B = Bg + (long)b * sB;
  const int bj = blockIdx.y;
  int biArr[2] = {(int)blockIdx.x, 31 - (int)blockIdx.x};

  __shared__ unsigned short As[128 * 32];
  __shared__ unsigned short Bs[128 * 32];

  const int tid = threadIdx.x;
  const int w = tid >> 6, l = tid & 63;
  const int wr = w >> 1, wc = w & 1;
  const int lr = l & 15;
  const int k8 = (l >> 4) * 8;
  const int rowB0 = bj * 128;

#pragma unroll
  for (int tt = 0; tt < 2; tt++) {
    const int bi = biArr[tt];
    const int rowA0 = bi * 128;
    int cap = (bi + 1) * 128;
    int Keff = cap < K ? cap : K;

    float4v acc[4][4];
#pragma unroll
    for (int i = 0; i < 4; i++)
#pragma unroll
      for (int j = 0; j < 4; j++) acc[i][j] = (float4v){0.f, 0.f, 0.f, 0.f};

    for (int k0 = 0; k0 < Keff; k0 += 32) {
#pragma unroll
      for (int i = 0; i < 2; i++) {
        int c = i * 256 + tid;
        int r = c >> 2, c8 = (c & 3) * 8;
        int ldsbase = (i * 256 + w * 64) * 8;
        gload_lds16(A + (long)(rowA0 + r) * K + k0 + c8, &As[ldsbase]);
        gload_lds16(B + (long)(rowB0 + r) * K + k0 + c8, &Bs[ldsbase]);
      }
      __syncthreads();

      short8 af[4], bf[4];
#pragma unroll
      for (int mi = 0; mi < 4; mi++)
        af[mi] = *(const short8*)&As[(wr * 64 + mi * 16 + lr) * 32 + k8];
#pragma unroll
      for (int ni = 0; ni < 4; ni++)
        bf[ni] = *(const short8*)&Bs[(wc * 64 + ni * 16 + lr) * 32 + k8];
#pragma unroll
      for (int mi = 0; mi < 4; mi++)
#pragma unroll
        for (int ni = 0; ni < 4; ni++)
          acc[mi][ni] = __builtin_amdgcn_mfma_f32_16x16x32_bf16(af[mi], bf[ni], acc[mi][ni], 0, 0, 0);
      __syncthreads();
    }

    float* C = Cg + (long)b * sC;
    const int col0 = bj * 128 + wc * 64;
    const int row0g = bi * 128 + wr * 64;
#pragma unroll
    for (int mi = 0; mi < 4; mi++) {
      int rbase = row0g + mi * 16 + (l >> 4) * 4;
#pragma unroll
      for (int ni = 0; ni < 4; ni++) {
        int col = col0 + ni * 16 + lr;
#pragma unroll
        for (int j = 0; j < 4; j++)
          C[(long)(rbase + j) * N + col] = acc[mi][ni][j];
      }
    }
  }
}

// ---------------- causal softmax, in place on bf16 S ----------------
__global__ __launch_bounds__(256) void softmax_causal(unsigned short* __restrict__ S) {
  const int bid = blockIdx.x;
  const int b = bid >> 12, i = bid & 4095;
  unsigned short* row = S + ((long)b * 4096 + i) * 4096;
  const int len = i + 1;
  const int padTo = ((i >> 7) + 1) << 7;
  const int nch = padTo >> 3;
  const int tid = threadIdx.x;
  const int w = tid >> 6;

  float v[2][8];
  int nc[2];
  float m = -3e38f;
#pragma unroll
  for (int s = 0; s < 2; s++) {
    int c = tid + s * 256;
    nc[s] = -1;
    if (c < nch) {
      nc[s] = c;
      short8 x = *(const short8*)&row[c * 8];
#pragma unroll
      for (int j = 0; j < 8; j++) {
        int idx = c * 8 + j;
        float f = (idx < len) ? b2f((unsigned short)x[j]) : -3e38f;
        v[s][j] = f;
        m = fmaxf(m, f);
      }
    }
  }

  __shared__ float red[4];
#pragma unroll
  for (int off = 32; off; off >>= 1) m = fmaxf(m, __shfl_xor(m, off));
  if ((tid & 63) == 0) red[w] = m;
  __syncthreads();
  m = fmaxf(fmaxf(red[0], red[1]), fmaxf(red[2], red[3]));

  float sum = 0.f;
#pragma unroll
  for (int s = 0; s < 2; s++) {
    if (nc[s] >= 0) {
#pragma unroll
      for (int j = 0; j < 8; j++) {
        float e = __expf(v[s][j] - m);
        v[s][j] = e;
        sum += e;
      }
    }
  }
  __syncthreads();
#pragma unroll
  for (int off = 32; off; off >>= 1) sum += __shfl_xor(sum, off);
  if ((tid & 63) == 0) red[w] = sum;
  __syncthreads();
  sum = red[0] + red[1] + red[2] + red[3];
  const float inv = 1.0f / sum;

#pragma unroll
  for (int s = 0; s < 2; s++) {
    if (nc[s] >= 0) {
      int c = nc[s];
      short8 o;
#pragma unroll
      for (int j = 0; j < 8; j++) o[j] = (short)f2b(v[s][j] * inv);
      *(short8*)&row[c * 8] = o;
    }
  }
}

// ---------------- v transpose: [4][4096][1024] -> [4][1024][4096] ----------------
__global__ __launch_bounds__(256) void transpose_v(const unsigned short* __restrict__ V,
                                                   unsigned short* __restrict__ VT) {
  __shared__ unsigned short t[64][65];
  const int b = blockIdx.z;
  const int n0 = blockIdx.x * 64;
  const int d0 = blockIdx.y * 64;
  const unsigned short* Vb = V + (long)b * 4096 * 1024;
  unsigned short* VTb = VT + (long)b * 1024 * 4096;
  const int tid = threadIdx.x;
#pragma unroll
  for (int s = 0; s < 2; s++) {
    int c = s * 256 + tid;
    int r = c >> 3, c8 = (c & 7) * 8;
    short8 x = *(const short8*)&Vb[(long)(n0 + r) * 1024 + d0 + c8];
#pragma unroll
    for (int j = 0; j < 8; j++) t[r][c8 + j] = (unsigned short)x[j];
  }
  __syncthreads();
#pragma unroll
  for (int s = 0; s < 2; s++) {
    int c = s * 256 + tid;
    int dr = c >> 3, n8 = (c & 7) * 8;
    short8 o;
#pragma unroll
    for (int j = 0; j < 8; j++) o[j] = (short)t[n8 + j][dr];
    *(short8*)&VTb[(long)(d0 + dr) * 4096 + n0 + n8] = o;
  }
}

extern "C" void kernel_launch(void* const* d_in, const int* in_sizes, int n_in,
                              void* d_out, int out_size, void* d_ws, size_t ws_size,
                              hipStream_t stream) {
  const float* x  = (const float*)d_in[0];
  const float* Wq = (const float*)d_in[1];
  const float* bq = (const float*)d_in[2];
  const float* Wk = (const float*)d_in[3];
  const float* bk = (const float*)d_in[4];
  const float* Wv = (const float*)d_in[5];
  const float* bv = (const float*)d_in[6];
  float* out = (float*)d_out;

  const long NTOK = 16384L;
  const long D = 1024L;
  const long NB = 4096L;

  unsigned short* ws = (unsigned short*)d_ws;
  unsigned short* qb = ws;                    // q|k|v contiguous 3x[16384,1024]
  unsigned short* kb = qb + NTOK * D;
  unsigned short* vb = kb + NTOK * D;
  unsigned short* vT = vb + NTOK * D;         // [4][1024][4096]
  unsigned short* S  = vT + NTOK * D;         // [4][4096][4096] bf16
  unsigned short* xb  = S;                    // overlaps S (consumed first)
  unsigned short* Wb  = S + NTOK * D;         // concat Wq|Wk|Wv [3072,1024]

  cvt_all<<<2048 + 3 * 256, 256, 0, stream>>>(x, Wq, Wk, Wv, xb, Wb);

  // QKV: [16384,1024] x [3072,1024]^T, 256^2 tiles
  gemm8p<0><<<dim3(64, 12), 512, 0, stream>>>(xb, Wb, bq, bk, bv, qb, 0, 0, 0);

  transpose_v<<<dim3(64, 16, 4), 256, 0, stream>>>(vb, vT);

  // S = q k^T per batch, lower-tri 256^2 tiles (136 per batch)
  gemm8p<1><<<544, 512, 0, stream>>>(qb, kb, nullptr, nullptr, nullptr, S,
      NB * D, NB * D, NB * NB);

  softmax_causal<<<16384, 256, 0, stream>>>(S);

  gemm_pv<<<dim3(16, 8, 4), 256, 0, stream>>>(S, vT, out,
      1024, 4096, NB * NB, D * NB, NB * D);
}

// Round 5
// 448.945 us; speedup vs baseline: 1.5759x; 1.1001x over previous
//
#include <hip/hip_runtime.h>
#include <hip/hip_bf16.h>
#include <stdint.h>

// SelfAttention: B=4, N=4096, D=1024, causal, fp32 in/out.
// R5 = R4 resubmit (R4 bench was an infra failure, no kernel signal).
// PV on 8-phase counted-vmcnt structure (BM=256,BN=128, paired bi/15-bi as one
// 68-tile K-stream, uniform work, 256 blocks = 1/CU). QKV + S on the R3 256^2
// 8-phase gemm8p. Softmax pads to 256-boundary.

typedef __attribute__((ext_vector_type(8))) short short8;
typedef __attribute__((ext_vector_type(4))) float float4v;

__device__ inline unsigned short f2b(float f) {
  union { float f; unsigned u; } v; v.f = f;
  unsigned r = (v.u + 0x7fffu + ((v.u >> 16) & 1u)) >> 16;
  return (unsigned short)r;
}
__device__ inline float b2f(unsigned short b) {
  union { unsigned u; float f; } v; v.u = ((unsigned)b) << 16;
  return v.f;
}

typedef const __attribute__((address_space(1))) unsigned int* gptr_t;
typedef __attribute__((address_space(3))) unsigned int* lptr_t;

__device__ inline void gload_lds16(const unsigned short* g, unsigned short* l) {
  __builtin_amdgcn_global_load_lds((gptr_t)(const void*)g, (lptr_t)(void*)l, 16, 0, 0);
}

// ---------------- f32 -> bf16 conversion, all 4 tensors in one launch --------
__global__ __launch_bounds__(256) void cvt_all(const float* __restrict__ x,
                                               const float* __restrict__ wq,
                                               const float* __restrict__ wk,
                                               const float* __restrict__ wv,
                                               unsigned short* __restrict__ xb,
                                               unsigned short* __restrict__ wb) {
  const float* src;
  unsigned short* dst;
  long n, i0, stride;
  if (blockIdx.x < 2048) {
    src = x; dst = xb; n = 16384L * 1024;
    i0 = ((long)blockIdx.x * 256 + threadIdx.x) * 4;
    stride = 2048L * 256 * 4;
  } else {
    int wsec = (blockIdx.x - 2048) >> 8;
    int blk = (blockIdx.x - 2048) & 255;
    src = wsec == 0 ? wq : (wsec == 1 ? wk : wv);
    dst = wb + (long)wsec * 1024 * 1024;
    n = 1024L * 1024;
    i0 = ((long)blk * 256 + threadIdx.x) * 4;
    stride = 256L * 256 * 4;
  }
  for (long i = i0; i < n; i += stride) {
    float4 f = *(const float4*)&src[i];
    union { unsigned short u[4]; uint2 v; } o;
    o.u[0] = f2b(f.x); o.u[1] = f2b(f.y); o.u[2] = f2b(f.z); o.u[3] = f2b(f.w);
    *(uint2*)&dst[i] = o.v;
  }
}

// ================= 256x256 / BK=64 / 8-wave 8-phase GEMM (QKV + S) ============
__device__ __forceinline__ void stage_half(const unsigned short* __restrict__ g,
                                           int grow0, int tile, int kk,
                                           char* tb, int tid) {
  const int kc = tile * 64 + kk * 32;
#pragma unroll
  for (int j = 0; j < 2; j++) {
    int c = j * 512 + tid;
    int lc = c ^ ((c >> 3) & 3);  // inverse of read-side swizzle, chunk-granular
    gload_lds16(g + (long)(grow0 + (lc >> 2)) * 1024 + kc + (lc & 3) * 8,
                (unsigned short*)(tb + kk * 16384 + (j * 512 + (tid & 448)) * 16));
  }
}

#define DSA(dst, TB, kk, mi) do { \
  int o = (kk) * 16384 + (wr * 128 + (mi) * 16 + lr) * 64 + g16; \
  o ^= ((o >> 3) & 0x30); dst = *(const short8*)((TB) + o); } while (0)
#define DSB(dst, TB, kk, ni) do { \
  int o = (kk) * 16384 + (wc * 64 + (ni) * 16 + lr) * 64 + g16; \
  o ^= ((o >> 3) & 0x30); dst = *(const short8*)((TB) + o); } while (0)

#define MF(x, y, z) __builtin_amdgcn_mfma_f32_16x16x32_bf16(x, y, z, 0, 0, 0)
#define MMQ(M0) \
  acc[M0 + 0][0] = MF(a0, b0, acc[M0 + 0][0]); \
  acc[M0 + 0][1] = MF(a0, b1, acc[M0 + 0][1]); \
  acc[M0 + 0][2] = MF(a0, b2, acc[M0 + 0][2]); \
  acc[M0 + 0][3] = MF(a0, b3, acc[M0 + 0][3]); \
  acc[M0 + 1][0] = MF(a1, b0, acc[M0 + 1][0]); \
  acc[M0 + 1][1] = MF(a1, b1, acc[M0 + 1][1]); \
  acc[M0 + 1][2] = MF(a1, b2, acc[M0 + 1][2]); \
  acc[M0 + 1][3] = MF(a1, b3, acc[M0 + 1][3]); \
  acc[M0 + 2][0] = MF(a2, b0, acc[M0 + 2][0]); \
  acc[M0 + 2][1] = MF(a2, b1, acc[M0 + 2][1]); \
  acc[M0 + 2][2] = MF(a2, b2, acc[M0 + 2][2]); \
  acc[M0 + 2][3] = MF(a2, b3, acc[M0 + 2][3]); \
  acc[M0 + 3][0] = MF(a3, b0, acc[M0 + 3][0]); \
  acc[M0 + 3][1] = MF(a3, b1, acc[M0 + 3][1]); \
  acc[M0 + 3][2] = MF(a3, b2, acc[M0 + 3][2]); \
  acc[M0 + 3][3] = MF(a3, b3, acc[M0 + 3][3]);

#define KTILE(AT, BT, OA, t) do { \
  short8 a0, a1, a2, a3, b0, b1, b2, b3; \
  DSB(b0, BT, 0, 0); DSB(b1, BT, 0, 1); DSB(b2, BT, 0, 2); DSB(b3, BT, 0, 3); \
  DSA(a0, AT, 0, 0); DSA(a1, AT, 0, 1); DSA(a2, AT, 0, 2); DSA(a3, AT, 0, 3); \
  if ((t) + 1 < NT) stage_half(A, rowA0, (t) + 1, 1, OA, tid); \
  __builtin_amdgcn_s_barrier(); \
  __builtin_amdgcn_s_setprio(1); MMQ(0); __builtin_amdgcn_s_setprio(0); \
  __builtin_amdgcn_s_barrier(); \
  DSA(a0, AT, 0, 4); DSA(a1, AT, 0, 5); DSA(a2, AT, 0, 6); DSA(a3, AT, 0, 7); \
  if ((t) + 2 < NT) stage_half(Bm, rowB0, (t) + 2, 0, BT, tid); \
  __builtin_amdgcn_s_barrier(); \
  __builtin_amdgcn_s_setprio(1); MMQ(4); __builtin_amdgcn_s_setprio(0); \
  __builtin_amdgcn_s_barrier(); \
  DSB(b0, BT, 1, 0); DSB(b1, BT, 1, 1); DSB(b2, BT, 1, 2); DSB(b3, BT, 1, 3); \
  DSA(a0, AT, 1, 0); DSA(a1, AT, 1, 1); DSA(a2, AT, 1, 2); DSA(a3, AT, 1, 3); \
  if ((t) + 2 < NT) stage_half(A, rowA0, (t) + 2, 0, AT, tid); \
  __builtin_amdgcn_s_barrier(); \
  __builtin_amdgcn_s_setprio(1); MMQ(0); __builtin_amdgcn_s_setprio(0); \
  __builtin_amdgcn_s_barrier(); \
  DSA(a0, AT, 1, 4); DSA(a1, AT, 1, 5); DSA(a2, AT, 1, 6); DSA(a3, AT, 1, 7); \
  if ((t) + 2 < NT) stage_half(Bm, rowB0, (t) + 2, 1, BT, tid); \
  __builtin_amdgcn_s_barrier(); \
  __builtin_amdgcn_s_setprio(1); MMQ(4); __builtin_amdgcn_s_setprio(0); \
  if ((t) + 2 < NT) { asm volatile("s_waitcnt vmcnt(6)" ::: "memory"); } \
  else               { asm volatile("s_waitcnt vmcnt(0)" ::: "memory"); } \
  __builtin_amdgcn_s_barrier(); \
} while (0)

template <int MODE>
__global__ __launch_bounds__(512, 2) void gemm8p(
    const unsigned short* __restrict__ Ag, const unsigned short* __restrict__ Bg,
    const float* __restrict__ b0v, const float* __restrict__ b1v,
    const float* __restrict__ b2v, void* __restrict__ Cg,
    long sA, long sB, long sC) {
  __shared__ __align__(16) char smem[131072];
  const int NT = 16;  // K=1024 / 64

  int bi, bj, b;
  if (MODE == 0) {
    bi = blockIdx.x; bj = blockIdx.y; b = 0;
  } else {
    int t = blockIdx.x % 136;
    b = blockIdx.x / 136;
    int r = (int)((sqrtf(8.0f * t + 1.0f) - 1.0f) * 0.5f);
    while ((r + 1) * (r + 2) / 2 <= t) r++;
    while (r * (r + 1) / 2 > t) r--;
    bi = r; bj = t - r * (r + 1) / 2;
  }

  const unsigned short* A = Ag + (long)b * sA;
  const unsigned short* Bm = Bg + (long)b * sB;

  const int tid = threadIdx.x;
  const int l = tid & 63, w = tid >> 6;
  const int wr = w >> 2, wc = w & 3;
  const int lr = l & 15, g16 = (l >> 4) * 16;
  const int rowA0 = bi * 256, rowB0 = bj * 256;

  char* A0 = smem;
  char* B0 = smem + 32768;
  char* A1 = smem + 65536;
  char* B1 = smem + 98304;

  float4v acc[8][4];
#pragma unroll
  for (int i = 0; i < 8; i++)
#pragma unroll
    for (int j = 0; j < 4; j++) acc[i][j] = (float4v){0.f, 0.f, 0.f, 0.f};

  stage_half(A, rowA0, 0, 0, A0, tid);
  stage_half(Bm, rowB0, 0, 0, B0, tid);
  stage_half(A, rowA0, 0, 1, A0, tid);
  stage_half(Bm, rowB0, 0, 1, B0, tid);
  stage_half(Bm, rowB0, 1, 0, B1, tid);
  stage_half(A, rowA0, 1, 0, A1, tid);
  stage_half(Bm, rowB0, 1, 1, B1, tid);
  asm volatile("s_waitcnt vmcnt(6)" ::: "memory");
  __builtin_amdgcn_s_barrier();

#pragma unroll 1
  for (int t = 0; t < NT; t += 2) {
    KTILE(A0, B0, A1, t);
    KTILE(A1, B1, A0, t + 1);
  }

  if (MODE == 0) {
    const int sec = bj >> 2;
    const float* bias = sec == 0 ? b0v : (sec == 1 ? b1v : b2v);
    const float scale = sec == 0 ? 0.03125f : 1.0f;
    unsigned short* C = (unsigned short*)Cg + (long)sec * 16777216L;
    const int colbase = (bj & 3) * 256 + wc * 64;
#pragma unroll
    for (int mi = 0; mi < 8; mi++) {
      int rbase = bi * 256 + wr * 128 + mi * 16 + (l >> 4) * 4;
#pragma unroll
      for (int ni = 0; ni < 4; ni++) {
        int col = colbase + ni * 16 + lr;
        float bb = bias[col];
#pragma unroll
        for (int j = 0; j < 4; j++)
          C[(long)(rbase + j) * 1024 + col] = f2b((acc[mi][ni][j] + bb) * scale);
      }
    }
  } else {
    unsigned short* C = (unsigned short*)Cg + (long)b * sC;
#pragma unroll
    for (int mi = 0; mi < 8; mi++) {
      int rbase = bi * 256 + wr * 128 + mi * 16 + (l >> 4) * 4;
#pragma unroll
      for (int ni = 0; ni < 4; ni++) {
        int col = bj * 256 + wc * 64 + ni * 16 + lr;
#pragma unroll
        for (int j = 0; j < 4; j++)
          C[(long)(rbase + j) * 4096 + col] = f2b(acc[mi][ni][j]);
      }
    }
  }
}

// ================= PV: 256x128, 8-phase, paired bi/15-bi K-stream =============
// A = S [4096,4096] bf16 (rows = out rows, cols = K). B = vT [1024,4096] bf16
// (rows = out cols d, cols = K). Per block: pair (bi,15-bi), 68 uniform K-tiles.
// LDS: A dbuf 2x32KB ([kk][256][64B], swizzled), B dbuf 2x16KB ([kk][128][64B]).

__device__ __forceinline__ void pv_src(int tt, int NT1, int bi, int bi2,
                                       int* ar, int* kc) {
  if (tt < NT1) { *ar = bi << 8; *kc = tt << 6; }
  else          { *ar = bi2 << 8; *kc = (tt - NT1) << 6; }
}

__device__ __forceinline__ void pv_stageA(const unsigned short* __restrict__ g,
                                          int ar, int kc, int kk, char* tb, int tid) {
#pragma unroll
  for (int j = 0; j < 2; j++) {
    int c = j * 512 + tid;
    int lc = c ^ ((c >> 3) & 3);
    gload_lds16(g + (long)(ar + (lc >> 2)) * 4096 + kc + kk * 32 + (lc & 3) * 8,
                (unsigned short*)(tb + kk * 16384 + (j * 512 + (tid & 448)) * 16));
  }
}

__device__ __forceinline__ void pv_stageB(const unsigned short* __restrict__ g,
                                          int br, int kc, char* tb, int tid) {
#pragma unroll
  for (int kk = 0; kk < 2; kk++) {
    int lc = tid ^ ((tid >> 3) & 3);
    gload_lds16(g + (long)(br + (lc >> 2)) * 4096 + kc + kk * 32 + (lc & 3) * 8,
                (unsigned short*)(tb + kk * 8192 + (tid & 448) * 16));
  }
}

#define PDSA(dst, TB, kk, mi) do { \
  int o = (kk) * 16384 + (wr * 64 + (mi) * 16 + lr) * 64 + g16; \
  o ^= ((o >> 3) & 0x30); dst = *(const short8*)((TB) + o); } while (0)
#define PDSB(dst, TB, kk, ni) do { \
  int o = (kk) * 8192 + (wc * 64 + (ni) * 16 + lr) * 64 + g16; \
  o ^= ((o >> 3) & 0x30); dst = *(const short8*)((TB) + o); } while (0)

#define PMM \
  acc[0][0] = MF(a0, b0, acc[0][0]); acc[0][1] = MF(a0, b1, acc[0][1]); \
  acc[0][2] = MF(a0, b2, acc[0][2]); acc[0][3] = MF(a0, b3, acc[0][3]); \
  acc[1][0] = MF(a1, b0, acc[1][0]); acc[1][1] = MF(a1, b1, acc[1][1]); \
  acc[1][2] = MF(a1, b2, acc[1][2]); acc[1][3] = MF(a1, b3, acc[1][3]); \
  acc[2][0] = MF(a2, b0, acc[2][0]); acc[2][1] = MF(a2, b1, acc[2][1]); \
  acc[2][2] = MF(a2, b2, acc[2][2]); acc[2][3] = MF(a2, b3, acc[2][3]); \
  acc[3][0] = MF(a3, b0, acc[3][0]); acc[3][1] = MF(a3, b1, acc[3][1]); \
  acc[3][2] = MF(a3, b2, acc[3][2]); acc[3][3] = MF(a3, b3, acc[3][3]);

// Per tile t reading CA/CB; OA/OB = other buffers.
// ph1 (kk0): reads + stage A-K1(t+1)->OA, B(t+1)->OB
// ph2 (kk1): reads + stage A-K0(t+2)->CA ; vmcnt(2) (never 0 mid-stream)
#define PVTILE(CA, CB, OA, OB, t) do { \
  short8 a0, a1, a2, a3, b0, b1, b2, b3; \
  PDSB(b0, CB, 0, 0); PDSB(b1, CB, 0, 1); PDSB(b2, CB, 0, 2); PDSB(b3, CB, 0, 3); \
  PDSA(a0, CA, 0, 0); PDSA(a1, CA, 0, 1); PDSA(a2, CA, 0, 2); PDSA(a3, CA, 0, 3); \
  if ((t) + 1 < 68) { \
    int ar_, kc_; pv_src((t) + 1, NT1, bi, bi2, &ar_, &kc_); \
    pv_stageA(Sb, ar_, kc_, 1, OA, tid); \
    pv_stageB(vTb, brow0, kc_, OB, tid); \
  } \
  __builtin_amdgcn_s_barrier(); \
  __builtin_amdgcn_s_setprio(1); PMM; __builtin_amdgcn_s_setprio(0); \
  __builtin_amdgcn_s_barrier(); \
  PDSB(b0, CB, 1, 0); PDSB(b1, CB, 1, 1); PDSB(b2, CB, 1, 2); PDSB(b3, CB, 1, 3); \
  PDSA(a0, CA, 1, 0); PDSA(a1, CA, 1, 1); PDSA(a2, CA, 1, 2); PDSA(a3, CA, 1, 3); \
  if ((t) + 2 < 68) { \
    int ar_, kc_; pv_src((t) + 2, NT1, bi, bi2, &ar_, &kc_); \
    pv_stageA(Sb, ar_, kc_, 0, CA, tid); \
  } \
  __builtin_amdgcn_s_barrier(); \
  __builtin_amdgcn_s_setprio(1); PMM; __builtin_amdgcn_s_setprio(0); \
  if ((t) + 2 < 68) { asm volatile("s_waitcnt vmcnt(2)" ::: "memory"); } \
  else              { asm volatile("s_waitcnt vmcnt(0)" ::: "memory"); } \
  __builtin_amdgcn_s_barrier(); \
} while (0)

#define PV_STORE(row0) do { \
  float* C = Cg + (long)b * 4194304L; \
  _Pragma("unroll") for (int mi = 0; mi < 4; mi++) { \
    int rbase = (row0) + wr * 64 + mi * 16 + (l >> 4) * 4; \
    _Pragma("unroll") for (int ni = 0; ni < 4; ni++) { \
      int col = brow0 + wc * 64 + ni * 16 + lr; \
      _Pragma("unroll") for (int j = 0; j < 4; j++) \
        C[(long)(rbase + j) * 1024 + col] = acc[mi][ni][j]; \
    } \
  } \
} while (0)

__global__ __launch_bounds__(512, 2) void pv8p(const unsigned short* __restrict__ Sg,
                                               const unsigned short* __restrict__ vTg,
                                               float* __restrict__ Cg) {
  __shared__ __align__(16) char smem[98304];
  const int bi = blockIdx.x;        // 0..7 (pairs with 15-bi)
  const int bj = blockIdx.y;        // 0..7 (128 d-cols each)
  const int b = blockIdx.z;
  const int bi2 = 15 - bi;
  const int NT1 = 4 * (bi + 1);     // even; NT1+NT2 = 68

  const unsigned short* Sb = Sg + (long)b * 16777216L;
  const unsigned short* vTb = vTg + (long)b * 4194304L;
  const int brow0 = bj * 128;

  const int tid = threadIdx.x;
  const int l = tid & 63, w = tid >> 6;
  const int wr = w >> 1, wc = w & 1;
  const int lr = l & 15, g16 = (l >> 4) * 16;

  char* XA = smem;                  // 32KB
  char* YA = smem + 32768;          // 32KB
  char* XB = smem + 65536;          // 16KB
  char* YB = smem + 81920;          // 16KB

  float4v acc[4][4];
#pragma unroll
  for (int i = 0; i < 4; i++)
#pragma unroll
    for (int j = 0; j < 4; j++) acc[i][j] = (float4v){0.f, 0.f, 0.f, 0.f};

  // prologue: tile0 full -> X (6 issues), tile1 A-K0 -> Y (2 issues)
  {
    int ar_, kc_;
    pv_src(0, NT1, bi, bi2, &ar_, &kc_);
    pv_stageA(Sb, ar_, kc_, 0, XA, tid);
    pv_stageA(Sb, ar_, kc_, 1, XA, tid);
    pv_stageB(vTb, brow0, kc_, XB, tid);
    pv_src(1, NT1, bi, bi2, &ar_, &kc_);
    pv_stageA(Sb, ar_, kc_, 0, YA, tid);
  }
  asm volatile("s_waitcnt vmcnt(2)" ::: "memory");
  __builtin_amdgcn_s_barrier();

#pragma unroll 1
  for (int t = 0; t < 68; t += 2) {
    if (t == NT1) {   // part-1 done (NT1 even): store + reset, stream continues
      PV_STORE(bi * 256);
#pragma unroll
      for (int i = 0; i < 4; i++)
#pragma unroll
        for (int j = 0; j < 4; j++) acc[i][j] = (float4v){0.f, 0.f, 0.f, 0.f};
    }
    PVTILE(XA, XB, YA, YB, t);
    PVTILE(YA, YB, XA, XB, t + 1);
  }
  PV_STORE(bi2 * 256);
}

// ---------------- causal softmax, in place on bf16 S (pad to 256-boundary) ---
__global__ __launch_bounds__(256) void softmax_causal(unsigned short* __restrict__ S) {
  const int bid = blockIdx.x;
  const int b = bid >> 12, i = bid & 4095;
  unsigned short* row = S + ((long)b * 4096 + i) * 4096;
  const int len = i + 1;
  const int padTo = ((i >> 8) + 1) << 8;  // 256-boundary for 256-row PV tiles
  const int nch = padTo >> 3;
  const int tid = threadIdx.x;
  const int w = tid >> 6;

  float v[2][8];
  int nc[2];
  float m = -3e38f;
#pragma unroll
  for (int s = 0; s < 2; s++) {
    int c = tid + s * 256;
    nc[s] = -1;
    if (c < nch) {
      nc[s] = c;
      short8 x = *(const short8*)&row[c * 8];
#pragma unroll
      for (int j = 0; j < 8; j++) {
        int idx = c * 8 + j;
        float f = (idx < len) ? b2f((unsigned short)x[j]) : -3e38f;
        v[s][j] = f;
        m = fmaxf(m, f);
      }
    }
  }

  __shared__ float red[4];
#pragma unroll
  for (int off = 32; off; off >>= 1) m = fmaxf(m, __shfl_xor(m, off));
  if ((tid & 63) == 0) red[w] = m;
  __syncthreads();
  m = fmaxf(fmaxf(red[0], red[1]), fmaxf(red[2], red[3]));

  float sum = 0.f;
#pragma unroll
  for (int s = 0; s < 2; s++) {
    if (nc[s] >= 0) {
#pragma unroll
      for (int j = 0; j < 8; j++) {
        float e = __expf(v[s][j] - m);
        v[s][j] = e;
        sum += e;
      }
    }
  }
  __syncthreads();
#pragma unroll
  for (int off = 32; off; off >>= 1) sum += __shfl_xor(sum, off);
  if ((tid & 63) == 0) red[w] = sum;
  __syncthreads();
  sum = red[0] + red[1] + red[2] + red[3];
  const float inv = 1.0f / sum;

#pragma unroll
  for (int s = 0; s < 2; s++) {
    if (nc[s] >= 0) {
      int c = nc[s];
      short8 o;
#pragma unroll
      for (int j = 0; j < 8; j++) o[j] = (short)f2b(v[s][j] * inv);
      *(short8*)&row[c * 8] = o;
    }
  }
}

// ---------------- v transpose: [4][4096][1024] -> [4][1024][4096] ------------
__global__ __launch_bounds__(256) void transpose_v(const unsigned short* __restrict__ V,
                                                   unsigned short* __restrict__ VT) {
  __shared__ unsigned short t[64][65];
  const int b = blockIdx.z;
  const int n0 = blockIdx.x * 64;
  const int d0 = blockIdx.y * 64;
  const unsigned short* Vb = V + (long)b * 4096 * 1024;
  unsigned short* VTb = VT + (long)b * 1024 * 4096;
  const int tid = threadIdx.x;
#pragma unroll
  for (int s = 0; s < 2; s++) {
    int c = s * 256 + tid;
    int r = c >> 3, c8 = (c & 7) * 8;
    short8 x = *(const short8*)&Vb[(long)(n0 + r) * 1024 + d0 + c8];
#pragma unroll
    for (int j = 0; j < 8; j++) t[r][c8 + j] = (unsigned short)x[j];
  }
  __syncthreads();
#pragma unroll
  for (int s = 0; s < 2; s++) {
    int c = s * 256 + tid;
    int dr = c >> 3, n8 = (c & 7) * 8;
    short8 o;
#pragma unroll
    for (int j = 0; j < 8; j++) o[j] = (short)t[n8 + j][dr];
    *(short8*)&VTb[(long)(d0 + dr) * 4096 + n0 + n8] = o;
  }
}

extern "C" void kernel_launch(void* const* d_in, const int* in_sizes, int n_in,
                              void* d_out, int out_size, void* d_ws, size_t ws_size,
                              hipStream_t stream) {
  const float* x  = (const float*)d_in[0];
  const float* Wq = (const float*)d_in[1];
  const float* bq = (const float*)d_in[2];
  const float* Wk = (const float*)d_in[3];
  const float* bk = (const float*)d_in[4];
  const float* Wv = (const float*)d_in[5];
  const float* bv = (const float*)d_in[6];
  float* out = (float*)d_out;

  const long NTOK = 16384L;
  const long D = 1024L;
  const long NB = 4096L;

  unsigned short* ws = (unsigned short*)d_ws;
  unsigned short* qb = ws;                    // q|k|v contiguous 3x[16384,1024]
  unsigned short* kb = qb + NTOK * D;
  unsigned short* vb = kb + NTOK * D;
  unsigned short* vT = vb + NTOK * D;         // [4][1024][4096]
  unsigned short* S  = vT + NTOK * D;         // [4][4096][4096] bf16
  unsigned short* xb  = S;                    // overlaps S (consumed first)
  unsigned short* Wb  = S + NTOK * D;         // concat Wq|Wk|Wv [3072,1024]

  cvt_all<<<2048 + 3 * 256, 256, 0, stream>>>(x, Wq, Wk, Wv, xb, Wb);

  gemm8p<0><<<dim3(64, 12), 512, 0, stream>>>(xb, Wb, bq, bk, bv, qb, 0, 0, 0);

  transpose_v<<<dim3(64, 16, 4), 256, 0, stream>>>(vb, vT);

  gemm8p<1><<<544, 512, 0, stream>>>(qb, kb, nullptr, nullptr, nullptr, S,
      NB * D, NB * D, NB * NB);

  softmax_causal<<<16384, 256, 0, stream>>>(S);

  pv8p<<<dim3(8, 8, 4), 512, 0, stream>>>(S, vT, out);
}